// Round 4
// baseline (86.503 us; speedup 1.0000x reference)
//
#include <hip/hip_runtime.h>

// out[b][o] = sum_d W[labels[b]][o][d] * vad[b][d]
// B=131072, OUT_DIM=768, IN_DIM=3, NUM_CLASSES=10, fp32.
// Write-roofline kernel (402.7 MB out). W (92,160 B) staged in LDS (SoA
// [l][d][o], conflict-free ds_read_b128) so the VMEM pipe carries only the
// store stream; labels/vad are wave-uniform scalar loads.

typedef float f32x4 __attribute__((ext_vector_type(4)));  // clang vector: OK for nontemporal builtin

#define B_TOTAL 131072
#define OUT_DIM 768
#define NCLS 10
#define W_ELEMS (NCLS * OUT_DIM * 3)          // 23040 floats = 92,160 B
#define BLOCK 1024
#define GRID 256
#define SAMPLES_PER_BLOCK (B_TOTAL / GRID)    // 512
#define WAVES_PER_BLOCK (BLOCK / 64)          // 16
#define SAMPLES_PER_WAVE (SAMPLES_PER_BLOCK / WAVES_PER_BLOCK)  // 32

__global__ __launch_bounds__(BLOCK) void vad_proj_kernel(
    const float* __restrict__ vad,     // (B, 3)
    const int*   __restrict__ labels,  // (B,)
    const float* __restrict__ W,       // (10, 768, 3)  row-major [l][o][d]
    float*       __restrict__ out)     // (B, 768)
{
    // SoA: wlds[l*2304 + d*768 + o] — a quad read (4 consecutive o) is one
    // ds_read_b128 with 16B lane stride -> 2 lanes/bank -> conflict-free.
    __shared__ float wlds[W_ELEMS];    // 92,160 B -> 1 block/CU, 16 waves/CU

    const int tid = threadIdx.x;

    // One-time stage + transpose: global [l][o][d] -> LDS [l][d][o]
    for (int g = tid; g < W_ELEMS; g += BLOCK) {
        const float val = W[g];
        const int l   = g / (OUT_DIM * 3);
        const int rem = g - l * (OUT_DIM * 3);
        const int o   = rem / 3;
        const int d   = rem - o * 3;
        wlds[l * (OUT_DIM * 3) + d * OUT_DIM + o] = val;
    }
    __syncthreads();

    const int lane = tid & 63;
    const int wave = __builtin_amdgcn_readfirstlane(tid >> 6);   // SGPR
    const int b0 = blockIdx.x * SAMPLES_PER_BLOCK + wave;        // wave-uniform

    #pragma unroll 2
    for (int j = 0; j < SAMPLES_PER_WAVE; ++j) {
        const int b = b0 + j * WAVES_PER_BLOCK;                  // uniform
        const int l = labels[b];                                 // scalar load
        const float* vb = vad + (size_t)b * 3;
        const float v0 = vb[0], v1 = vb[1], v2 = vb[2];          // scalar loads

        const float* base = wlds + l * (OUT_DIM * 3);
        f32x4* obase = (f32x4*)(out + (size_t)b * OUT_DIM);

        #pragma unroll
        for (int k = 0; k < 3; ++k) {
            const int q = lane + 64 * k;                         // quad index
            const f32x4 wd0 = *(const f32x4*)(base + 0 * OUT_DIM + 4 * q);
            const f32x4 wd1 = *(const f32x4*)(base + 1 * OUT_DIM + 4 * q);
            const f32x4 wd2 = *(const f32x4*)(base + 2 * OUT_DIM + 4 * q);
            f32x4 o = wd0 * v0 + wd1 * v1 + wd2 * v2;
            __builtin_nontemporal_store(o, obase + q);           // write-only stream
        }
    }
}

extern "C" void kernel_launch(void* const* d_in, const int* in_sizes, int n_in,
                              void* d_out, int out_size, void* d_ws, size_t ws_size,
                              hipStream_t stream) {
    const float* vad    = (const float*)d_in[0];
    const int*   labels = (const int*)d_in[1];
    const float* W      = (const float*)d_in[2];
    float*       out    = (float*)d_out;

    // 256 blocks x 1024 threads, 1 block/CU (92KB LDS), 512 samples/block.
    vad_proj_kernel<<<GRID, BLOCK, 0, stream>>>(vad, labels, W, out);
}

// Round 5
// 84.881 us; speedup vs baseline: 1.0191x; 1.0191x over previous
//
#include <hip/hip_runtime.h>

// out[b][o] = sum_d W[labels[b]][o][d] * vad[b][d]
// B=131072, OUT_DIM=768, IN_DIM=3, NUM_CLASSES=10, fp32.
// Write-bound (402.7 MB out). This round: 4-sample batches per wave iteration
// -> operands gathered first (independent scalar loads + 36 indep. 16B W
// loads), then a 12-store / 12KB back-to-back burst to maximize in-flight
// store bytes per wave (testing the store-queue-depth hypothesis).

typedef float f32x4 __attribute__((ext_vector_type(4)));

#define B_TOTAL 131072
#define OUT_DIM 768
#define NWAVES 8192                    // 2048 blocks x 4 waves
#define SAMPLES_PER_WAVE 16            // 131072 / 8192
#define BATCH 4                        // samples gathered before the store burst

__global__ __launch_bounds__(256) void vad_proj_kernel(
    const float* __restrict__ vad,     // (B, 3)
    const int*   __restrict__ labels,  // (B,)
    const float* __restrict__ W,       // (10, 768, 3) row-major [l][o][d]
    float*       __restrict__ out)     // (B, 768)
{
    const int lane = threadIdx.x & 63;
    const int wave = __builtin_amdgcn_readfirstlane((int)(threadIdx.x >> 6)); // SGPR
    const int b0 = blockIdx.x * 4 + wave;  // wave-uniform

    #pragma unroll 2
    for (int t = 0; t < SAMPLES_PER_WAVE / BATCH; ++t) {
        f32x4 acc[BATCH][3];
        int   bs[BATCH];

        // ---- gather + compute phase: all loads independent across u ----
        #pragma unroll
        for (int u = 0; u < BATCH; ++u) {
            const int b = b0 + (t * BATCH + u) * NWAVES;   // uniform
            bs[u] = b;
            const int l = labels[b];                        // scalar load
            const float* vb = vad + (size_t)b * 3;
            const float v0 = vb[0], v1 = vb[1], v2 = vb[2]; // scalar loads

            const f32x4* wp = (const f32x4*)(W + (size_t)l * (OUT_DIM * 3));
            #pragma unroll
            for (int k = 0; k < 3; ++k) {
                const int q = lane + 64 * k;               // quad index
                const f32x4 w0 = wp[q * 3 + 0];            // 48B/lane contiguous
                const f32x4 w1 = wp[q * 3 + 1];
                const f32x4 w2 = wp[q * 3 + 2];
                f32x4 o;
                o.x = w0.x * v0 + w0.y * v1 + w0.z * v2;
                o.y = w0.w * v0 + w1.x * v1 + w1.y * v2;
                o.z = w1.z * v0 + w1.w * v1 + w2.x * v2;
                o.w = w2.y * v0 + w2.z * v1 + w2.w * v2;
                acc[u][k] = o;
            }
        }

        // ---- store burst: 12 x 1KB wave-stores back-to-back (12KB in flight) ----
        #pragma unroll
        for (int u = 0; u < BATCH; ++u) {
            f32x4* obase = (f32x4*)(out + (size_t)bs[u] * OUT_DIM);
            #pragma unroll
            for (int k = 0; k < 3; ++k) {
                obase[lane + 64 * k] = acc[u][k];
            }
        }
    }
}

extern "C" void kernel_launch(void* const* d_in, const int* in_sizes, int n_in,
                              void* d_out, int out_size, void* d_ws, size_t ws_size,
                              hipStream_t stream) {
    const float* vad    = (const float*)d_in[0];
    const int*   labels = (const int*)d_in[1];
    const float* W      = (const float*)d_in[2];
    float*       out    = (float*)d_out;

    vad_proj_kernel<<<2048, 256, 0, stream>>>(vad, labels, W, out);
}